// Round 2
// baseline (509.626 us; speedup 1.0000x reference)
//
#include <hip/hip_runtime.h>

// ---------------- problem constants ----------------
#define BATCH 2
#define SEQ 2048
#define DMODEL 2048
#define NHEADS 16
#define NKV 4
#define DK 128
#define WINH 64   // WINDOW/2

typedef unsigned short ushort_t;
typedef __attribute__((ext_vector_type(8))) __bf16 bf16x8;
typedef __attribute__((ext_vector_type(4))) float f32x4;

__device__ __forceinline__ float b2f(ushort_t u) {
    union { unsigned int i; float f; } v; v.i = ((unsigned int)u) << 16; return v.f;
}
__device__ __forceinline__ ushort_t f2b(float f) {
    union { float f; unsigned int i; } v; v.f = f;
    unsigned int r = v.i + 0x7FFFu + ((v.i >> 16) & 1u);
    return (ushort_t)(r >> 16);
}

// ---------------------------------------------------------------
// f32 -> bf16 cast, 8 elements/thread. n8 = n/8.
// ---------------------------------------------------------------
__global__ __launch_bounds__(256) void cvt_bf16(
    const float* __restrict__ src, ushort_t* __restrict__ dst, int n8)
{
    int i = blockIdx.x * 256 + threadIdx.x;
    if (i >= n8) return;
    float4 a = *((const float4*)src + i * 2);
    float4 b = *((const float4*)src + i * 2 + 1);
    ushort_t o[8] = { f2b(a.x), f2b(a.y), f2b(a.z), f2b(a.w),
                      f2b(b.x), f2b(b.y), f2b(b.z), f2b(b.w) };
    *((uint4*)dst + i) = *(const uint4*)o;
}

__global__ __launch_bounds__(256) void concat_bias(
    const float* __restrict__ bk, const float* __restrict__ bv,
    float* __restrict__ dst)
{
    int i = blockIdx.x * 256 + threadIdx.x;
    if (i < 512) dst[i] = bk[i];
    else if (i < 1024) dst[i] = bv[i - 512];
}

// ---------------------------------------------------------------
// GEMM: C[M][N] = A[M][K] * W[N][K]^T + bias[N]; bf16 in, f32 acc.
// 128x128 tile, BK=32, 4 waves (2x2 of 64x64), mfma_f32_16x16x32_bf16.
// LDS: 16B chunks, chunk(r,kg) at index (r*4) | (kg ^ (r&3)).
// OT = ushort_t (bf16 out) or float.
// ---------------------------------------------------------------
template <typename OT>
__global__ __launch_bounds__(256) void gemm_bt(
    const ushort_t* __restrict__ A, const ushort_t* __restrict__ W,
    const float* __restrict__ bias, OT* __restrict__ C,
    int M, int N, int K)
{
    __shared__ __attribute__((aligned(16))) ushort_t sA[4096];
    __shared__ __attribute__((aligned(16))) ushort_t sB[4096];

    const int tid  = threadIdx.x;
    const int lane = tid & 63;
    const int wave = tid >> 6;
    const int nbn  = N >> 7;
    const int bm   = blockIdx.x / nbn;
    const int bn   = blockIdx.x % nbn;
    const int m0   = bm << 7, n0 = bn << 7;
    const int wm   = wave >> 1, wn = wave & 1;

    f32x4 acc[4][4] = {};

    const int frow = lane & 15;
    const int kg   = lane >> 4;           // 0..3 -> k offset kg*8

    const int c0 = tid,       r0 = c0 >> 2, g0 = c0 & 3;
    const int c1 = tid + 256, r1 = c1 >> 2, g1 = c1 & 3;
    const ushort_t* Ar0 = A + (size_t)(m0 + r0) * K + g0 * 8;
    const ushort_t* Ar1 = A + (size_t)(m0 + r1) * K + g1 * 8;
    const ushort_t* Wr0 = W + (size_t)(n0 + r0) * K + g0 * 8;
    const ushort_t* Wr1 = W + (size_t)(n0 + r1) * K + g1 * 8;
    const int sw0 = ((r0 << 2) | (g0 ^ (r0 & 3))) << 3;
    const int sw1 = ((r1 << 2) | (g1 ^ (r1 & 3))) << 3;

    for (int k0 = 0; k0 < K; k0 += 32) {
        uint4 a0 = *(const uint4*)(Ar0 + k0);
        uint4 a1 = *(const uint4*)(Ar1 + k0);
        uint4 b0 = *(const uint4*)(Wr0 + k0);
        uint4 b1 = *(const uint4*)(Wr1 + k0);
        __syncthreads();
        *(uint4*)(sA + sw0) = a0;
        *(uint4*)(sA + sw1) = a1;
        *(uint4*)(sB + sw0) = b0;
        *(uint4*)(sB + sw1) = b1;
        __syncthreads();

        bf16x8 af[4], bfr[4];
#pragma unroll
        for (int mi = 0; mi < 4; ++mi) {
            int r = (wm << 6) + (mi << 4) + frow;
            af[mi] = *(const bf16x8*)(sA + (((r << 2) | (kg ^ (r & 3))) << 3));
        }
#pragma unroll
        for (int ni = 0; ni < 4; ++ni) {
            int r = (wn << 6) + (ni << 4) + frow;
            bfr[ni] = *(const bf16x8*)(sB + (((r << 2) | (kg ^ (r & 3))) << 3));
        }
#pragma unroll
        for (int mi = 0; mi < 4; ++mi)
#pragma unroll
            for (int ni = 0; ni < 4; ++ni)
                acc[mi][ni] = __builtin_amdgcn_mfma_f32_16x16x32_bf16(
                    af[mi], bfr[ni], acc[mi][ni], 0, 0, 0);
    }

    // D: col = lane&15, row = (lane>>4)*4 + reg  [m89-verified]
    const int orow = (lane >> 4) << 2;
    const int ocol = lane & 15;
#pragma unroll
    for (int ni = 0; ni < 4; ++ni) {
        int col = n0 + (wn << 6) + (ni << 4) + ocol;
        float bvf = bias[col];
#pragma unroll
        for (int mi = 0; mi < 4; ++mi) {
#pragma unroll
            for (int r = 0; r < 4; ++r) {
                int row = m0 + (wm << 6) + (mi << 4) + orow + r;
                float val = acc[mi][ni][r] + bvf;
                if constexpr (sizeof(OT) == 2) C[(size_t)row * N + col] = f2b(val);
                else                           C[(size_t)row * N + col] = val;
            }
        }
    }
}

// ---------------------------------------------------------------
// Fused RMSNorm + RoPE, IN-PLACE. One 128-thread block per (b,s,slot).
// Slots 0..15 = q heads in q0 [B*S][2048]; 16..19 = k heads in kv0
// [B*S][1024] (cols 0..511 = k). v untouched.
// ---------------------------------------------------------------
__global__ __launch_bounds__(128) void rmsrope(
    ushort_t* __restrict__ q0, ushort_t* __restrict__ kv0,
    const float* __restrict__ qw, const float* __restrict__ kw)
{
    __shared__ float red[2];
    const int d   = threadIdx.x;           // 0..127
    const int blk = blockIdx.x;
    const int bs  = blk / 20;
    const int hh  = blk % 20;
    const int s   = bs & 2047;

    ushort_t* p; const float* w;
    if (hh < NHEADS) { p = q0 + (size_t)bs * DMODEL + hh * DK;          w = qw; }
    else             { p = kv0 + (size_t)bs * (2 * NKV * DK) + (hh - NHEADS) * DK; w = kw; }

    float x  = b2f(p[d]);
    float ss = x * x;
#pragma unroll
    for (int off = 32; off; off >>= 1) ss += __shfl_xor(ss, off, 64);
    if ((d & 63) == 0) red[d >> 6] = ss;
    __syncthreads();
    float tot = red[0] + red[1];
    float inv = rsqrtf(tot * (1.0f / 128.0f) + 1e-8f);
    float xn  = x * inv * w[d];

    float partner = __shfl_xor(xn, 1, 64);
    float invfreq = powf(10000.0f, -(float)(d & ~1) / 128.0f);
    float angle   = (float)s * invfreq;
    float c = cosf(angle), sn = sinf(angle);
    float o = (d & 1) ? (partner * sn + xn * c) : (xn * c - partner * sn);
    p[d] = f2b(o);
}

// ---------------------------------------------------------------
// Windowed causal GQA attention. One wave per query (b,h,i).
// q0: [B*S][2048] (post rms+rope); kv0: [B*S][1024] (k | v).
// exp(-10000 - m) == 0 in f32, so window-only softmax is exact.
// ---------------------------------------------------------------
__global__ __launch_bounds__(256) void attn_win(
    const ushort_t* __restrict__ q0, const ushort_t* __restrict__ kv0,
    const float* __restrict__ scp, ushort_t* __restrict__ ao)
{
    const int lane = threadIdx.x & 63;
    const int gw   = (blockIdx.x << 2) + (threadIdx.x >> 6);
    const int i = gw & 2047;
    const int h = (gw >> 11) & 15;
    const int b = gw >> 15;
    const int g = h >> 2;                    // kv head
    const float scale = scp[0];
    const int d0 = lane << 1;
    const size_t row = ((size_t)b << 11) + i;

    const ushort_t* qp = q0 + row * DMODEL + h * DK + d0;
    float q0f = b2f(qp[0]), q1f = b2f(qp[1]);
    const ushort_t* kbase = kv0 + ((size_t)b << 11) * 1024 + g * DK + d0;

    float m = -1e30f, l = 0.f, a0 = 0.f, a1 = 0.f;
    int jlo = i - WINH; if (jlo < 0) jlo = 0;
    for (int j = jlo; j <= i; ++j) {
        const ushort_t* kj = kbase + (size_t)j * 1024;
        unsigned int kk = *(const unsigned int*)kj;
        unsigned int vv = *(const unsigned int*)(kj + 512);
        float p = q0f * b2f((ushort_t)kk) + q1f * b2f((ushort_t)(kk >> 16));
#pragma unroll
        for (int off = 32; off; off >>= 1) p += __shfl_xor(p, off, 64);
        float sc = p * scale;
        float mn = fmaxf(m, sc);
        float corr = __expf(m - mn);
        float e    = __expf(sc - mn);
        l  = l * corr + e;
        a0 = a0 * corr + e * b2f((ushort_t)vv);
        a1 = a1 * corr + e * b2f((ushort_t)(vv >> 16));
        m = mn;
    }
    float rl = 1.0f / l;
    unsigned int outw = (unsigned int)f2b(a0 * rl) | ((unsigned int)f2b(a1 * rl) << 16);
    *(unsigned int*)(ao + row * DMODEL + (h << 7) + d0) = outw;
}

// ---------------------------------------------------------------
extern "C" void kernel_launch(void* const* d_in, const int* in_sizes, int n_in,
                              void* d_out, int out_size, void* d_ws, size_t ws_size,
                              hipStream_t stream)
{
    const float* x   = (const float*)d_in[0];
    const float* Wq  = (const float*)d_in[1];
    const float* bq  = (const float*)d_in[2];
    const float* Wk  = (const float*)d_in[3];
    const float* bk  = (const float*)d_in[4];
    const float* Wv  = (const float*)d_in[5];
    const float* bv  = (const float*)d_in[6];
    const float* Wo  = (const float*)d_in[7];
    const float* bo  = (const float*)d_in[8];
    const float* qnw = (const float*)d_in[9];
    const float* knw = (const float*)d_in[10];
    const float* scp = (const float*)d_in[11];
    float* out = (float*)d_out;

    const int M = BATCH * SEQ;             // 4096
    ushort_t* xb   = (ushort_t*)d_ws;                       // M x 2048 (later: ao)
    ushort_t* q0   = xb  + (size_t)M * DMODEL;              // M x 2048
    ushort_t* kv0  = q0  + (size_t)M * DMODEL;              // M x 1024
    ushort_t* Wqb  = kv0 + (size_t)M * 1024;                // 2048 x 2048
    ushort_t* Wkvb = Wqb + (size_t)DMODEL * DMODEL;         // 1024 x 2048
    ushort_t* Wob  = Wkvb + (size_t)1024 * DMODEL;          // 2048 x 2048
    float*    bkv  = (float*)(Wob + (size_t)DMODEL * DMODEL); // 1024 f32
    ushort_t* ao   = xb;
    (void)ws_size; (void)in_sizes; (void)n_in; (void)out_size;

    cvt_bf16<<<dim3(4096), 256, 0, stream>>>(x,  xb,   M * DMODEL / 8);
    cvt_bf16<<<dim3(2048), 256, 0, stream>>>(Wq, Wqb,  DMODEL * DMODEL / 8);
    cvt_bf16<<<dim3(512),  256, 0, stream>>>(Wk, Wkvb, 512 * DMODEL / 8);
    cvt_bf16<<<dim3(512),  256, 0, stream>>>(Wv, Wkvb + (size_t)512 * DMODEL, 512 * DMODEL / 8);
    cvt_bf16<<<dim3(2048), 256, 0, stream>>>(Wo, Wob,  DMODEL * DMODEL / 8);
    concat_bias<<<dim3(4), 256, 0, stream>>>(bk, bv, bkv);

    gemm_bt<ushort_t><<<dim3((M / 128) * (DMODEL / 128)), 256, 0, stream>>>(xb, Wqb, bq, q0, M, DMODEL, DMODEL);
    gemm_bt<ushort_t><<<dim3((M / 128) * (1024 / 128)),   256, 0, stream>>>(xb, Wkvb, bkv, kv0, M, 1024, DMODEL);
    rmsrope<<<dim3(M * (NHEADS + NKV)), 128, 0, stream>>>(q0, kv0, qnw, knw);
    attn_win<<<dim3((BATCH * NHEADS * SEQ) / 4), 256, 0, stream>>>(q0, kv0, scp, ao);
    gemm_bt<float><<<dim3((M / 128) * (DMODEL / 128)), 256, 0, stream>>>(ao, Wob, bo, out, M, DMODEL, DMODEL);
}

// Round 4
// 231.433 us; speedup vs baseline: 2.2020x; 2.2020x over previous
//
#include <hip/hip_runtime.h>

// ---------------- problem constants ----------------
#define BATCH 2
#define SEQ 2048
#define DMODEL 2048
#define NHEADS 16
#define NKV 4
#define DK 128
#define WINH 64   // WINDOW/2

typedef unsigned short ushort_t;
typedef __attribute__((ext_vector_type(8))) __bf16 bf16x8;
typedef __attribute__((ext_vector_type(4))) float f32x4;

__device__ __forceinline__ float b2f(ushort_t u) {
    union { unsigned int i; float f; } v; v.i = ((unsigned int)u) << 16; return v.f;
}
__device__ __forceinline__ ushort_t f2b(float f) {
    union { float f; unsigned int i; } v; v.f = f;
    unsigned int r = v.i + 0x7FFFu + ((v.i >> 16) & 1u);
    return (ushort_t)(r >> 16);
}

// ---------------------------------------------------------------
// f32 -> bf16 cast, 8 elements/thread. n8 = n/8.
// ---------------------------------------------------------------
__global__ __launch_bounds__(256) void cvt_bf16(
    const float* __restrict__ src, ushort_t* __restrict__ dst, int n8)
{
    int i = blockIdx.x * 256 + threadIdx.x;
    if (i >= n8) return;
    float4 a = *((const float4*)src + i * 2);
    float4 b = *((const float4*)src + i * 2 + 1);
    ushort_t o[8] = { f2b(a.x), f2b(a.y), f2b(a.z), f2b(a.w),
                      f2b(b.x), f2b(b.y), f2b(b.z), f2b(b.w) };
    *((uint4*)dst + i) = *(const uint4*)o;
}

__global__ __launch_bounds__(256) void concat_bias(
    const float* __restrict__ bk, const float* __restrict__ bv,
    float* __restrict__ dst)
{
    int i = blockIdx.x * 256 + threadIdx.x;
    if (i < 512) dst[i] = bk[i];
    else if (i < 1024) dst[i] = bv[i - 512];
}

// ---------------------------------------------------------------
// GEMM: C[M][N] = A[M][K] * W[N][K]^T + bias[N]; bf16 in, f32 acc.
// 128x128 tile, BK=32, 4 waves (2x2 of 64x64), mfma_f32_16x16x32_bf16.
// ---------------------------------------------------------------
template <typename OT>
__global__ __launch_bounds__(256) void gemm_bt(
    const ushort_t* __restrict__ A, const ushort_t* __restrict__ W,
    const float* __restrict__ bias, OT* __restrict__ C,
    int M, int N, int K)
{
    __shared__ __attribute__((aligned(16))) ushort_t sA[4096];
    __shared__ __attribute__((aligned(16))) ushort_t sB[4096];

    const int tid  = threadIdx.x;
    const int lane = tid & 63;
    const int wave = tid >> 6;
    const int nbn  = N >> 7;
    const int bm   = blockIdx.x / nbn;
    const int bn   = blockIdx.x % nbn;
    const int m0   = bm << 7, n0 = bn << 7;
    const int wm   = wave >> 1, wn = wave & 1;

    f32x4 acc[4][4] = {};

    const int frow = lane & 15;
    const int kg   = lane >> 4;

    const int c0 = tid,       r0 = c0 >> 2, g0 = c0 & 3;
    const int c1 = tid + 256, r1 = c1 >> 2, g1 = c1 & 3;
    const ushort_t* Ar0 = A + (size_t)(m0 + r0) * K + g0 * 8;
    const ushort_t* Ar1 = A + (size_t)(m0 + r1) * K + g1 * 8;
    const ushort_t* Wr0 = W + (size_t)(n0 + r0) * K + g0 * 8;
    const ushort_t* Wr1 = W + (size_t)(n0 + r1) * K + g1 * 8;
    const int sw0 = ((r0 << 2) | (g0 ^ (r0 & 3))) << 3;
    const int sw1 = ((r1 << 2) | (g1 ^ (r1 & 3))) << 3;

    for (int k0 = 0; k0 < K; k0 += 32) {
        uint4 a0 = *(const uint4*)(Ar0 + k0);
        uint4 a1 = *(const uint4*)(Ar1 + k0);
        uint4 b0 = *(const uint4*)(Wr0 + k0);
        uint4 b1 = *(const uint4*)(Wr1 + k0);
        __syncthreads();
        *(uint4*)(sA + sw0) = a0;
        *(uint4*)(sA + sw1) = a1;
        *(uint4*)(sB + sw0) = b0;
        *(uint4*)(sB + sw1) = b1;
        __syncthreads();

        bf16x8 af[4], bfr[4];
#pragma unroll
        for (int mi = 0; mi < 4; ++mi) {
            int r = (wm << 6) + (mi << 4) + frow;
            af[mi] = *(const bf16x8*)(sA + (((r << 2) | (kg ^ (r & 3))) << 3));
        }
#pragma unroll
        for (int ni = 0; ni < 4; ++ni) {
            int r = (wn << 6) + (ni << 4) + frow;
            bfr[ni] = *(const bf16x8*)(sB + (((r << 2) | (kg ^ (r & 3))) << 3));
        }
#pragma unroll
        for (int mi = 0; mi < 4; ++mi)
#pragma unroll
            for (int ni = 0; ni < 4; ++ni)
                acc[mi][ni] = __builtin_amdgcn_mfma_f32_16x16x32_bf16(
                    af[mi], bfr[ni], acc[mi][ni], 0, 0, 0);
    }

    const int orow = (lane >> 4) << 2;
    const int ocol = lane & 15;
#pragma unroll
    for (int ni = 0; ni < 4; ++ni) {
        int col = n0 + (wn << 6) + (ni << 4) + ocol;
        float bvf = bias[col];
#pragma unroll
        for (int mi = 0; mi < 4; ++mi) {
#pragma unroll
            for (int r = 0; r < 4; ++r) {
                int row = m0 + (wm << 6) + (mi << 4) + orow + r;
                float val = acc[mi][ni][r] + bvf;
                if constexpr (sizeof(OT) == 2) C[(size_t)row * N + col] = f2b(val);
                else                           C[(size_t)row * N + col] = val;
            }
        }
    }
}

// ---------------------------------------------------------------
// Fused RMSNorm + RoPE, IN-PLACE.
// ---------------------------------------------------------------
__global__ __launch_bounds__(128) void rmsrope(
    ushort_t* __restrict__ q0, ushort_t* __restrict__ kv0,
    const float* __restrict__ qw, const float* __restrict__ kw)
{
    __shared__ float red[2];
    const int d   = threadIdx.x;           // 0..127
    const int blk = blockIdx.x;
    const int bs  = blk / 20;
    const int hh  = blk % 20;
    const int s   = bs & 2047;

    ushort_t* p; const float* w;
    if (hh < NHEADS) { p = q0 + (size_t)bs * DMODEL + hh * DK;          w = qw; }
    else             { p = kv0 + (size_t)bs * (2 * NKV * DK) + (hh - NHEADS) * DK; w = kw; }

    float x  = b2f(p[d]);
    float ss = x * x;
#pragma unroll
    for (int off = 32; off; off >>= 1) ss += __shfl_xor(ss, off, 64);
    if ((d & 63) == 0) red[d >> 6] = ss;
    __syncthreads();
    float tot = red[0] + red[1];
    float inv = rsqrtf(tot * (1.0f / 128.0f) + 1e-8f);
    float xn  = x * inv * w[d];

    float partner = __shfl_xor(xn, 1, 64);
    // invfreq = 10000^(-(d&~1)/128) = exp2(-(d&~1) * log2(10000)/128)
    float invfreq = exp2f(-(float)(d & ~1) * (13.287712379549449f / 128.0f));
    float angle   = (float)s * invfreq;
    float c = cosf(angle), sn = sinf(angle);
    float o = (d & 1) ? (partner * sn + xn * c) : (xn * c - partner * sn);
    p[d] = f2b(o);
}

// ---------------------------------------------------------------
// MFMA windowed-causal GQA attention.
// Block = 256 thr (4 waves), handles 64 queries of one (b,h).
// Key window union = [i0-64, i0+63] = exactly 128 keys.
// Wave w owns 16 queries. LDS: K[128key][128d] (32KB, reused as P f32
// after barrier) + VT[128d][128key] (32KB). Chunk-XOR swizzles keep all
// ds traffic <=2-way. exp(-1e30)==0 matches ref's -10000 fill exactly.
// ---------------------------------------------------------------
__global__ __launch_bounds__(256) void attn_mfma(
    const ushort_t* __restrict__ q0, const ushort_t* __restrict__ kv0,
    const float* __restrict__ scp, ushort_t* __restrict__ ao)
{
    __shared__ __attribute__((aligned(16))) ushort_t sK[16384];   // 32KB: K tile, then P(f32)
    __shared__ __attribute__((aligned(16))) ushort_t sVT[16384];  // 32KB: V^T tile

    const int tid  = threadIdx.x;
    const int lane = tid & 63;
    const int w    = tid >> 6;
    const int c    = lane & 15;
    const int g    = lane >> 4;

    const int blk = blockIdx.x;
    const int qt  = blk & 31;
    const int h   = (blk >> 5) & 15;
    const int b   = blk >> 9;
    const int kvh = h >> 2;
    const int i0  = qt << 6;
    const int jb  = i0 - 64;
    const float scale = scp[0];

    // ---- Q fragments straight from global ----
    bf16x8 aq[4];
    {
        const ushort_t* qp = q0 + ((size_t)(b * 2048 + i0 + w * 16 + c)) * 2048
                                + h * 128 + g * 8;
#pragma unroll
        for (int ks = 0; ks < 4; ++ks)
            aq[ks] = *(const bf16x8*)(qp + ks * 32);
    }

    // ---- stage K rows [key][d] ----
    const ushort_t* kvb = kv0 + ((size_t)b * 2048) * 1024 + kvh * 128;
#pragma unroll
    for (int it = 0; it < 8; ++it) {
        int idx = it * 256 + tid;
        int rr = idx >> 4, cc = idx & 15;
        int j = jb + rr; if (j < 0) j = 0;
        uint4 val = *(const uint4*)(kvb + (size_t)j * 1024 + cc * 8);
        int f2v = (rr & 15) ^ ((rr >> 3) & 15);
        *(uint4*)(sK + (rr * 16 + (cc ^ f2v)) * 8) = val;
    }
    // ---- stage V transposed: VT[d][key], pair-packed b32 writes ----
#pragma unroll
    for (int it = 0; it < 4; ++it) {
        int task = it * 256 + tid;
        int pp = task >> 4, d8 = task & 15;       // key pair pp, d-chunk d8
        int j0 = jb + 2 * pp;     if (j0 < 0) j0 = 0;
        int j1 = jb + 2 * pp + 1; if (j1 < 0) j1 = 0;
        ushort_t e0[8]; *(uint4*)e0 = *(const uint4*)(kvb + (size_t)j0 * 1024 + 512 + d8 * 8);
        ushort_t e1[8]; *(uint4*)e1 = *(const uint4*)(kvb + (size_t)j1 * 1024 + 512 + d8 * 8);
        int cc = pp >> 2;
#pragma unroll
        for (int jj = 0; jj < 8; ++jj) {
            int rr = d8 * 8 + jj;
            int f2v = (rr & 15) ^ ((rr >> 3) & 15);
            unsigned int word = (unsigned int)e0[jj] | ((unsigned int)e1[jj] << 16);
            *(unsigned int*)(sVT + (rr * 16 + (cc ^ f2v)) * 8 + (pp & 3) * 2) = word;
        }
    }
    __syncthreads();

    // ---- S = Q K^T : lane holds S[q=4g+r][key=16nt+c] ----
    f32x4 s[8] = {};
#pragma unroll
    for (int nt = 0; nt < 8; ++nt) {
        int rr = nt * 16 + c;
        int f2v = (rr & 15) ^ ((rr >> 3) & 15);
#pragma unroll
        for (int ks = 0; ks < 4; ++ks) {
            bf16x8 bk = *(const bf16x8*)(sK + (rr * 16 + ((ks * 4 + g) ^ f2v)) * 8);
            s[nt] = __builtin_amdgcn_mfma_f32_16x16x32_bf16(aq[ks], bk, s[nt], 0, 0, 0);
        }
    }

    // ---- mask + row softmax (per reg r) ----
    float linv[4];
#pragma unroll
    for (int r = 0; r < 4; ++r) {
        int qb = w * 16 + g * 4 + r;
#pragma unroll
        for (int nt = 0; nt < 8; ++nt) {
            int jl = nt * 16 + c;
            bool valid = (jl >= qb) && (jl <= qb + 64) && (i0 + jl >= 64);
            s[nt][r] = valid ? s[nt][r] * scale : -1e30f;
        }
        float m = s[0][r];
#pragma unroll
        for (int nt = 1; nt < 8; ++nt) m = fmaxf(m, s[nt][r]);
#pragma unroll
        for (int off = 1; off <= 8; off <<= 1) m = fmaxf(m, __shfl_xor(m, off, 64));
        float sum = 0.f;
#pragma unroll
        for (int nt = 0; nt < 8; ++nt) {
            float e = __expf(s[nt][r] - m);
            s[nt][r] = e;
            sum += e;
        }
#pragma unroll
        for (int off = 1; off <= 8; off <<= 1) sum += __shfl_xor(sum, off, 64);
        linv[r] = 1.0f / sum;
    }

    // ---- P round-trip through LDS (K region, all waves past K reads) ----
    __syncthreads();
    float* Pw = (float*)sK + w * 2048;   // own 16 x 128 f32 region
#pragma unroll
    for (int nt = 0; nt < 8; ++nt) {
#pragma unroll
        for (int r = 0; r < 4; ++r) {
            int q = g * 4 + r;
            int chunk = nt * 4 + (c >> 2);
            Pw[q * 128 + ((chunk ^ (q & 7)) * 4) + (c & 3)] = s[nt][r];
        }
    }

    // ---- O = P V : A-frag from own P rows, B-frag from VT ----
    f32x4 o[8] = {};
#pragma unroll
    for (int kt = 0; kt < 4; ++kt) {
        float pf[8];
#pragma unroll
        for (int e = 0; e < 2; ++e) {
            int chunk = kt * 8 + g * 2 + e;
            f32x4 v4 = *(const f32x4*)(Pw + c * 128 + ((chunk ^ (c & 7)) * 4));
            pf[e * 4 + 0] = v4[0]; pf[e * 4 + 1] = v4[1];
            pf[e * 4 + 2] = v4[2]; pf[e * 4 + 3] = v4[3];
        }
        ushort_t pb[8];
#pragma unroll
        for (int j = 0; j < 8; ++j) pb[j] = f2b(pf[j]);
        bf16x8 pa = *(const bf16x8*)pb;
#pragma unroll
        for (int dt = 0; dt < 8; ++dt) {
            int rr = dt * 16 + c;
            int f2v = (rr & 15) ^ ((rr >> 3) & 15);
            bf16x8 bv = *(const bf16x8*)(sVT + (rr * 16 + ((kt * 4 + g) ^ f2v)) * 8);
            o[dt] = __builtin_amdgcn_mfma_f32_16x16x32_bf16(pa, bv, o[dt], 0, 0, 0);
        }
    }

    // ---- epilogue: normalize + store bf16 ----
    const size_t orow0 = (size_t)(b * 2048 + i0 + w * 16);
#pragma unroll
    for (int dt = 0; dt < 8; ++dt) {
#pragma unroll
        for (int r = 0; r < 4; ++r) {
            int q = g * 4 + r;
            ao[(orow0 + q) * 2048 + h * 128 + dt * 16 + c] = f2b(o[dt][r] * linv[r]);
        }
    }
}

// ---------------------------------------------------------------
extern "C" void kernel_launch(void* const* d_in, const int* in_sizes, int n_in,
                              void* d_out, int out_size, void* d_ws, size_t ws_size,
                              hipStream_t stream)
{
    const float* x   = (const float*)d_in[0];
    const float* Wq  = (const float*)d_in[1];
    const float* bq  = (const float*)d_in[2];
    const float* Wk  = (const float*)d_in[3];
    const float* bk  = (const float*)d_in[4];
    const float* Wv  = (const float*)d_in[5];
    const float* bv  = (const float*)d_in[6];
    const float* Wo  = (const float*)d_in[7];
    const float* bo  = (const float*)d_in[8];
    const float* qnw = (const float*)d_in[9];
    const float* knw = (const float*)d_in[10];
    const float* scp = (const float*)d_in[11];
    float* out = (float*)d_out;

    const int M = BATCH * SEQ;             // 4096
    ushort_t* xb   = (ushort_t*)d_ws;                       // M x 2048 (later: ao)
    ushort_t* q0   = xb  + (size_t)M * DMODEL;              // M x 2048
    ushort_t* kv0  = q0  + (size_t)M * DMODEL;              // M x 1024
    ushort_t* Wqb  = kv0 + (size_t)M * 1024;                // 2048 x 2048
    ushort_t* Wkvb = Wqb + (size_t)DMODEL * DMODEL;         // 1024 x 2048
    ushort_t* Wob  = Wkvb + (size_t)1024 * DMODEL;          // 2048 x 2048
    float*    bkv  = (float*)(Wob + (size_t)DMODEL * DMODEL); // 1024 f32
    ushort_t* ao   = xb;
    (void)ws_size; (void)in_sizes; (void)n_in; (void)out_size;

    cvt_bf16<<<dim3(4096), 256, 0, stream>>>(x,  xb,   M * DMODEL / 8);
    cvt_bf16<<<dim3(2048), 256, 0, stream>>>(Wq, Wqb,  DMODEL * DMODEL / 8);
    cvt_bf16<<<dim3(512),  256, 0, stream>>>(Wk, Wkvb, 512 * DMODEL / 8);
    cvt_bf16<<<dim3(512),  256, 0, stream>>>(Wv, Wkvb + (size_t)512 * DMODEL, 512 * DMODEL / 8);
    cvt_bf16<<<dim3(2048), 256, 0, stream>>>(Wo, Wob,  DMODEL * DMODEL / 8);
    concat_bias<<<dim3(4), 256, 0, stream>>>(bk, bv, bkv);

    gemm_bt<ushort_t><<<dim3((M / 128) * (DMODEL / 128)), 256, 0, stream>>>(xb, Wqb, bq, q0, M, DMODEL, DMODEL);
    gemm_bt<ushort_t><<<dim3((M / 128) * (1024 / 128)),   256, 0, stream>>>(xb, Wkvb, bkv, kv0, M, 1024, DMODEL);
    rmsrope<<<dim3(M * (NHEADS + NKV)), 128, 0, stream>>>(q0, kv0, qnw, knw);
    attn_mfma<<<dim3(BATCH * NHEADS * (SEQ / 64)), 256, 0, stream>>>(q0, kv0, scp, ao);
    gemm_bt<float><<<dim3((M / 128) * (DMODEL / 128)), 256, 0, stream>>>(ao, Wob, bo, out, M, DMODEL, DMODEL);
}

// Round 5
// 210.415 us; speedup vs baseline: 2.4220x; 1.0999x over previous
//
#include <hip/hip_runtime.h>

// ---------------- problem constants ----------------
#define BATCH 2
#define SEQ 2048
#define DMODEL 2048
#define NHEADS 16
#define NKV 4
#define DK 128
#define WINH 64   // WINDOW/2

typedef unsigned short ushort_t;
typedef __attribute__((ext_vector_type(8))) __bf16 bf16x8;
typedef __attribute__((ext_vector_type(4))) float f32x4;

__device__ __forceinline__ float b2f(ushort_t u) {
    union { unsigned int i; float f; } v; v.i = ((unsigned int)u) << 16; return v.f;
}
__device__ __forceinline__ ushort_t f2b(float f) {
    union { float f; unsigned int i; } v; v.f = f;
    unsigned int r = v.i + 0x7FFFu + ((v.i >> 16) & 1u);
    return (ushort_t)(r >> 16);
}

// async global->LDS, 16B per lane; LDS dest is wave-uniform base + lane*16.
__device__ __forceinline__ void gload_lds16(const ushort_t* g, ushort_t* l) {
    __builtin_amdgcn_global_load_lds(
        (__attribute__((address_space(1))) void*)(void*)const_cast<ushort_t*>(g),
        (__attribute__((address_space(3))) void*)l, 16, 0, 0);
}

// ---------------------------------------------------------------
// f32 -> bf16 cast, 8 elements/thread. n8 = n/8.
// ---------------------------------------------------------------
__global__ __launch_bounds__(256) void cvt_bf16(
    const float* __restrict__ src, ushort_t* __restrict__ dst, int n8)
{
    int i = blockIdx.x * 256 + threadIdx.x;
    if (i >= n8) return;
    float4 a = *((const float4*)src + i * 2);
    float4 b = *((const float4*)src + i * 2 + 1);
    ushort_t o[8] = { f2b(a.x), f2b(a.y), f2b(a.z), f2b(a.w),
                      f2b(b.x), f2b(b.y), f2b(b.z), f2b(b.w) };
    *((uint4*)dst + i) = *(const uint4*)o;
}

__global__ __launch_bounds__(256) void concat_bias(
    const float* __restrict__ bk, const float* __restrict__ bv,
    float* __restrict__ dst)
{
    int i = blockIdx.x * 256 + threadIdx.x;
    if (i < 512) dst[i] = bk[i];
    else if (i < 1024) dst[i] = bv[i - 512];
}

// ---------------------------------------------------------------
// GEMM: C[M][N] = A[M][K] * W[N][K]^T + bias[N]; bf16 in, f32 acc.
// 128x128 tile, BK=32, 4 waves (2x2 of 64x64), mfma_f32_16x16x32_bf16.
// m97 structure: global_load_lds width=16, linear LDS dest, pre-swizzled
// global source. Swizzle: chunk (r,kg) stored at slot = kg ^ ((r>>1)&3)
// -> ds_read_b128 <=2-way (free), writes structural-minimum.
// 2-barrier K-loop (compiler drains vmcnt(0) before s_barrier).
// ---------------------------------------------------------------
template <typename OT>
__global__ __launch_bounds__(256) void gemm_bt(
    const ushort_t* __restrict__ A, const ushort_t* __restrict__ W,
    const float* __restrict__ bias, OT* __restrict__ C,
    int M, int N, int K)
{
    __shared__ __attribute__((aligned(16))) ushort_t sA[4096];
    __shared__ __attribute__((aligned(16))) ushort_t sB[4096];

    const int tid  = threadIdx.x;
    const int lane = tid & 63;
    const int wave = tid >> 6;
    const int nbn  = N >> 7;
    const int bm   = blockIdx.x / nbn;
    const int bn   = blockIdx.x % nbn;
    const int m0   = bm << 7, n0 = bn << 7;
    const int wm   = wave >> 1, wn = wave & 1;

    f32x4 acc[4][4] = {};

    const int frow = lane & 15;
    const int kg   = lane >> 4;           // k slot 0..3 (8 bf16 each)

    // staging: tile = 512 x 16B chunks; position p = r*4 + slot,
    // slot = kg ^ ((r>>1)&3). Wave w issues chunks {2w,2w+1} x {A,B}:
    // 1KB each, LDS dest uniform, per-lane global src inverse-swizzled.
    const int cc0 = wave * 2, cc1 = wave * 2 + 1;
    const int p0 = cc0 * 64 + lane, p1 = cc1 * 64 + lane;
    const int r0 = p0 >> 2,        r1 = p1 >> 2;
    const int kg0 = (p0 & 3) ^ ((r0 >> 1) & 3);
    const int kg1 = (p1 & 3) ^ ((r1 >> 1) & 3);
    const ushort_t* gA0 = A + (size_t)(m0 + r0) * K + kg0 * 8;
    const ushort_t* gA1 = A + (size_t)(m0 + r1) * K + kg1 * 8;
    const ushort_t* gB0 = W + (size_t)(n0 + r0) * K + kg0 * 8;
    const ushort_t* gB1 = W + (size_t)(n0 + r1) * K + kg1 * 8;
    ushort_t* lA0 = sA + cc0 * 512;
    ushort_t* lA1 = sA + cc1 * 512;
    ushort_t* lB0 = sB + cc0 * 512;
    ushort_t* lB1 = sB + cc1 * 512;

    for (int k0 = 0; k0 < K; k0 += 32) {
        if (k0) __syncthreads();             // prev-iter LDS reads drained
        gload_lds16(gA0 + k0, lA0);
        gload_lds16(gA1 + k0, lA1);
        gload_lds16(gB0 + k0, lB0);
        gload_lds16(gB1 + k0, lB1);
        __syncthreads();                     // loads landed (vmcnt(0) drain)

        bf16x8 af[4], bfr[4];
#pragma unroll
        for (int mi = 0; mi < 4; ++mi) {
            int r = (wm << 6) + (mi << 4) + frow;
            int slot = kg ^ ((r >> 1) & 3);
            af[mi] = *(const bf16x8*)(sA + (((r << 2) | slot) << 3));
        }
#pragma unroll
        for (int ni = 0; ni < 4; ++ni) {
            int r = (wn << 6) + (ni << 4) + frow;
            int slot = kg ^ ((r >> 1) & 3);
            bfr[ni] = *(const bf16x8*)(sB + (((r << 2) | slot) << 3));
        }
#pragma unroll
        for (int mi = 0; mi < 4; ++mi)
#pragma unroll
            for (int ni = 0; ni < 4; ++ni)
                acc[mi][ni] = __builtin_amdgcn_mfma_f32_16x16x32_bf16(
                    af[mi], bfr[ni], acc[mi][ni], 0, 0, 0);
    }

    // D: col = lane&15, row = (lane>>4)*4 + reg  [m89-verified]
    const int orow = (lane >> 4) << 2;
    const int ocol = lane & 15;
#pragma unroll
    for (int ni = 0; ni < 4; ++ni) {
        int col = n0 + (wn << 6) + (ni << 4) + ocol;
        float bvf = bias[col];
#pragma unroll
        for (int mi = 0; mi < 4; ++mi) {
#pragma unroll
            for (int r = 0; r < 4; ++r) {
                int row = m0 + (wm << 6) + (mi << 4) + orow + r;
                float val = acc[mi][ni][r] + bvf;
                if constexpr (sizeof(OT) == 2) C[(size_t)row * N + col] = f2b(val);
                else                           C[(size_t)row * N + col] = val;
            }
        }
    }
}

// ---------------------------------------------------------------
// Fused RMSNorm + RoPE, IN-PLACE.
// ---------------------------------------------------------------
__global__ __launch_bounds__(128) void rmsrope(
    ushort_t* __restrict__ q0, ushort_t* __restrict__ kv0,
    const float* __restrict__ qw, const float* __restrict__ kw)
{
    __shared__ float red[2];
    const int d   = threadIdx.x;           // 0..127
    const int blk = blockIdx.x;
    const int bs  = blk / 20;
    const int hh  = blk % 20;
    const int s   = bs & 2047;

    ushort_t* p; const float* w;
    if (hh < NHEADS) { p = q0 + (size_t)bs * DMODEL + hh * DK;          w = qw; }
    else             { p = kv0 + (size_t)bs * (2 * NKV * DK) + (hh - NHEADS) * DK; w = kw; }

    float x  = b2f(p[d]);
    float ss = x * x;
#pragma unroll
    for (int off = 32; off; off >>= 1) ss += __shfl_xor(ss, off, 64);
    if ((d & 63) == 0) red[d >> 6] = ss;
    __syncthreads();
    float tot = red[0] + red[1];
    float inv = rsqrtf(tot * (1.0f / 128.0f) + 1e-8f);
    float xn  = x * inv * w[d];

    float partner = __shfl_xor(xn, 1, 64);
    // invfreq = 10000^(-(d&~1)/128) = exp2(-(d&~1) * log2(10000)/128)
    float invfreq = exp2f(-(float)(d & ~1) * (13.287712379549449f / 128.0f));
    float angle   = (float)s * invfreq;
    float c = cosf(angle), sn = sinf(angle);
    float o = (d & 1) ? (partner * sn + xn * c) : (xn * c - partner * sn);
    p[d] = f2b(o);
}

// ---------------------------------------------------------------
// MFMA windowed-causal GQA attention.
// Block = 256 thr (4 waves), handles 64 queries of one (b,h).
// Key window union = [i0-64, i0+63] = exactly 128 keys.
// ---------------------------------------------------------------
__global__ __launch_bounds__(256) void attn_mfma(
    const ushort_t* __restrict__ q0, const ushort_t* __restrict__ kv0,
    const float* __restrict__ scp, ushort_t* __restrict__ ao)
{
    __shared__ __attribute__((aligned(16))) ushort_t sK[16384];   // 32KB: K tile, then P(f32)
    __shared__ __attribute__((aligned(16))) ushort_t sVT[16384];  // 32KB: V^T tile

    const int tid  = threadIdx.x;
    const int lane = tid & 63;
    const int w    = tid >> 6;
    const int c    = lane & 15;
    const int g    = lane >> 4;

    const int blk = blockIdx.x;
    const int qt  = blk & 31;
    const int h   = (blk >> 5) & 15;
    const int b   = blk >> 9;
    const int kvh = h >> 2;
    const int i0  = qt << 6;
    const int jb  = i0 - 64;
    const float scale = scp[0];

    // ---- Q fragments straight from global ----
    bf16x8 aq[4];
    {
        const ushort_t* qp = q0 + ((size_t)(b * 2048 + i0 + w * 16 + c)) * 2048
                                + h * 128 + g * 8;
#pragma unroll
        for (int ks = 0; ks < 4; ++ks)
            aq[ks] = *(const bf16x8*)(qp + ks * 32);
    }

    // ---- stage K rows [key][d] ----
    const ushort_t* kvb = kv0 + ((size_t)b * 2048) * 1024 + kvh * 128;
#pragma unroll
    for (int it = 0; it < 8; ++it) {
        int idx = it * 256 + tid;
        int rr = idx >> 4, cc = idx & 15;
        int j = jb + rr; if (j < 0) j = 0;
        uint4 val = *(const uint4*)(kvb + (size_t)j * 1024 + cc * 8);
        int f2v = (rr & 15) ^ ((rr >> 3) & 15);
        *(uint4*)(sK + (rr * 16 + (cc ^ f2v)) * 8) = val;
    }
    // ---- stage V transposed: VT[d][key], pair-packed b32 writes ----
#pragma unroll
    for (int it = 0; it < 4; ++it) {
        int task = it * 256 + tid;
        int pp = task >> 4, d8 = task & 15;       // key pair pp, d-chunk d8
        int j0 = jb + 2 * pp;     if (j0 < 0) j0 = 0;
        int j1 = jb + 2 * pp + 1; if (j1 < 0) j1 = 0;
        ushort_t e0[8]; *(uint4*)e0 = *(const uint4*)(kvb + (size_t)j0 * 1024 + 512 + d8 * 8);
        ushort_t e1[8]; *(uint4*)e1 = *(const uint4*)(kvb + (size_t)j1 * 1024 + 512 + d8 * 8);
        int cc = pp >> 2;
#pragma unroll
        for (int jj = 0; jj < 8; ++jj) {
            int rr = d8 * 8 + jj;
            int f2v = (rr & 15) ^ ((rr >> 3) & 15);
            unsigned int word = (unsigned int)e0[jj] | ((unsigned int)e1[jj] << 16);
            *(unsigned int*)(sVT + (rr * 16 + (cc ^ f2v)) * 8 + (pp & 3) * 2) = word;
        }
    }
    __syncthreads();

    // ---- S = Q K^T : lane holds S[q=4g+r][key=16nt+c] ----
    f32x4 s[8] = {};
#pragma unroll
    for (int nt = 0; nt < 8; ++nt) {
        int rr = nt * 16 + c;
        int f2v = (rr & 15) ^ ((rr >> 3) & 15);
#pragma unroll
        for (int ks = 0; ks < 4; ++ks) {
            bf16x8 bk = *(const bf16x8*)(sK + (rr * 16 + ((ks * 4 + g) ^ f2v)) * 8);
            s[nt] = __builtin_amdgcn_mfma_f32_16x16x32_bf16(aq[ks], bk, s[nt], 0, 0, 0);
        }
    }

    // ---- mask + row softmax (per reg r) ----
    float linv[4];
#pragma unroll
    for (int r = 0; r < 4; ++r) {
        int qb = w * 16 + g * 4 + r;
#pragma unroll
        for (int nt = 0; nt < 8; ++nt) {
            int jl = nt * 16 + c;
            bool valid = (jl >= qb) && (jl <= qb + 64) && (i0 + jl >= 64);
            s[nt][r] = valid ? s[nt][r] * scale : -1e30f;
        }
        float m = s[0][r];
#pragma unroll
        for (int nt = 1; nt < 8; ++nt) m = fmaxf(m, s[nt][r]);
#pragma unroll
        for (int off = 1; off <= 8; off <<= 1) m = fmaxf(m, __shfl_xor(m, off, 64));
        float sum = 0.f;
#pragma unroll
        for (int nt = 0; nt < 8; ++nt) {
            float e = __expf(s[nt][r] - m);
            s[nt][r] = e;
            sum += e;
        }
#pragma unroll
        for (int off = 1; off <= 8; off <<= 1) sum += __shfl_xor(sum, off, 64);
        linv[r] = 1.0f / sum;
    }

    // ---- P round-trip through LDS (K region, all waves past K reads) ----
    __syncthreads();
    float* Pw = (float*)sK + w * 2048;   // own 16 x 128 f32 region
#pragma unroll
    for (int nt = 0; nt < 8; ++nt) {
#pragma unroll
        for (int r = 0; r < 4; ++r) {
            int q = g * 4 + r;
            int chunk = nt * 4 + (c >> 2);
            Pw[q * 128 + ((chunk ^ (q & 7)) * 4) + (c & 3)] = s[nt][r];
        }
    }

    // ---- O = P V : A-frag from own P rows, B-frag from VT ----
    f32x4 o[8] = {};
#pragma unroll
    for (int kt = 0; kt < 4; ++kt) {
        float pf[8];
#pragma unroll
        for (int e = 0; e < 2; ++e) {
            int chunk = kt * 8 + g * 2 + e;
            f32x4 v4 = *(const f32x4*)(Pw + c * 128 + ((chunk ^ (c & 7)) * 4));
            pf[e * 4 + 0] = v4[0]; pf[e * 4 + 1] = v4[1];
            pf[e * 4 + 2] = v4[2]; pf[e * 4 + 3] = v4[3];
        }
        ushort_t pb[8];
#pragma unroll
        for (int j = 0; j < 8; ++j) pb[j] = f2b(pf[j]);
        bf16x8 pa = *(const bf16x8*)pb;
#pragma unroll
        for (int dt = 0; dt < 8; ++dt) {
            int rr = dt * 16 + c;
            int f2v = (rr & 15) ^ ((rr >> 3) & 15);
            bf16x8 bv = *(const bf16x8*)(sVT + (rr * 16 + ((kt * 4 + g) ^ f2v)) * 8);
            o[dt] = __builtin_amdgcn_mfma_f32_16x16x32_bf16(pa, bv, o[dt], 0, 0, 0);
        }
    }

    // ---- epilogue: normalize + store bf16 ----
    const size_t orow0 = (size_t)(b * 2048 + i0 + w * 16);
#pragma unroll
    for (int dt = 0; dt < 8; ++dt) {
#pragma unroll
        for (int r = 0; r < 4; ++r) {
            int q = g * 4 + r;
            ao[(orow0 + q) * 2048 + h * 128 + dt * 16 + c] = f2b(o[dt][r] * linv[r]);
        }
    }
}

// ---------------------------------------------------------------
extern "C" void kernel_launch(void* const* d_in, const int* in_sizes, int n_in,
                              void* d_out, int out_size, void* d_ws, size_t ws_size,
                              hipStream_t stream)
{
    const float* x   = (const float*)d_in[0];
    const float* Wq  = (const float*)d_in[1];
    const float* bq  = (const float*)d_in[2];
    const float* Wk  = (const float*)d_in[3];
    const float* bk  = (const float*)d_in[4];
    const float* Wv  = (const float*)d_in[5];
    const float* bv  = (const float*)d_in[6];
    const float* Wo  = (const float*)d_in[7];
    const float* bo  = (const float*)d_in[8];
    const float* qnw = (const float*)d_in[9];
    const float* knw = (const float*)d_in[10];
    const float* scp = (const float*)d_in[11];
    float* out = (float*)d_out;

    const int M = BATCH * SEQ;             // 4096
    ushort_t* xb   = (ushort_t*)d_ws;                       // M x 2048 (later: ao)
    ushort_t* q0   = xb  + (size_t)M * DMODEL;              // M x 2048
    ushort_t* kv0  = q0  + (size_t)M * DMODEL;              // M x 1024
    ushort_t* Wqb  = kv0 + (size_t)M * 1024;                // 2048 x 2048
    ushort_t* Wkvb = Wqb + (size_t)DMODEL * DMODEL;         // 1024 x 2048
    ushort_t* Wob  = Wkvb + (size_t)1024 * DMODEL;          // 2048 x 2048
    float*    bkv  = (float*)(Wob + (size_t)DMODEL * DMODEL); // 1024 f32
    ushort_t* ao   = xb;
    (void)ws_size; (void)in_sizes; (void)n_in; (void)out_size;

    cvt_bf16<<<dim3(4096), 256, 0, stream>>>(x,  xb,   M * DMODEL / 8);
    cvt_bf16<<<dim3(2048), 256, 0, stream>>>(Wq, Wqb,  DMODEL * DMODEL / 8);
    cvt_bf16<<<dim3(512),  256, 0, stream>>>(Wk, Wkvb, 512 * DMODEL / 8);
    cvt_bf16<<<dim3(512),  256, 0, stream>>>(Wv, Wkvb + (size_t)512 * DMODEL, 512 * DMODEL / 8);
    cvt_bf16<<<dim3(2048), 256, 0, stream>>>(Wo, Wob,  DMODEL * DMODEL / 8);
    concat_bias<<<dim3(4), 256, 0, stream>>>(bk, bv, bkv);

    gemm_bt<ushort_t><<<dim3((M / 128) * (DMODEL / 128)), 256, 0, stream>>>(xb, Wqb, bq, q0, M, DMODEL, DMODEL);
    gemm_bt<ushort_t><<<dim3((M / 128) * (1024 / 128)),   256, 0, stream>>>(xb, Wkvb, bkv, kv0, M, 1024, DMODEL);
    rmsrope<<<dim3(M * (NHEADS + NKV)), 128, 0, stream>>>(q0, kv0, qnw, knw);
    attn_mfma<<<dim3(BATCH * NHEADS * (SEQ / 64)), 256, 0, stream>>>(q0, kv0, scp, ao);
    gemm_bt<float><<<dim3((M / 128) * (DMODEL / 128)), 256, 0, stream>>>(ao, Wob, bo, out, M, DMODEL, DMODEL);
}

// Round 6
// 164.982 us; speedup vs baseline: 3.0890x; 1.2754x over previous
//
#include <hip/hip_runtime.h>

// ---------------- problem constants ----------------
#define BATCH 2
#define SEQ 2048
#define DMODEL 2048
#define NHEADS 16
#define NKV 4
#define DK 128
#define WINH 64   // WINDOW/2
#define NQKV 3072 // 2048 q + 512 k + 512 v

typedef unsigned short ushort_t;
typedef __attribute__((ext_vector_type(8))) __bf16 bf16x8;
typedef __attribute__((ext_vector_type(4))) float f32x4;

__device__ __forceinline__ float b2f(ushort_t u) {
    union { unsigned int i; float f; } v; v.i = ((unsigned int)u) << 16; return v.f;
}
__device__ __forceinline__ ushort_t f2b(float f) {
    union { float f; unsigned int i; } v; v.f = f;
    unsigned int r = v.i + 0x7FFFu + ((v.i >> 16) & 1u);
    return (ushort_t)(r >> 16);
}

// async global->LDS, 16B/lane; LDS dest wave-uniform base + lane*16.
__device__ __forceinline__ void gload_lds16(const ushort_t* g, ushort_t* l) {
    __builtin_amdgcn_global_load_lds(
        (__attribute__((address_space(1))) void*)(void*)const_cast<ushort_t*>(g),
        (__attribute__((address_space(3))) void*)l, 16, 0, 0);
}

// ---------------------------------------------------------------
// f32 -> bf16 cast, 8 elements/thread.
// ---------------------------------------------------------------
__global__ __launch_bounds__(256) void cvt_bf16(
    const float* __restrict__ src, ushort_t* __restrict__ dst, int n8)
{
    int i = blockIdx.x * 256 + threadIdx.x;
    if (i >= n8) return;
    float4 a = *((const float4*)src + i * 2);
    float4 b = *((const float4*)src + i * 2 + 1);
    ushort_t o[8] = { f2b(a.x), f2b(a.y), f2b(a.z), f2b(a.w),
                      f2b(b.x), f2b(b.y), f2b(b.z), f2b(b.w) };
    *((uint4*)dst + i) = *(const uint4*)o;
}

// All four weight matrices -> one contiguous bf16 region:
// rows 0..2047 Wq | 2048..2559 Wk | 2560..3071 Wv | 3072..5119 Wo.
__global__ __launch_bounds__(256) void cvt_weights(
    const float* __restrict__ Wq, const float* __restrict__ Wk,
    const float* __restrict__ Wv, const float* __restrict__ Wo,
    ushort_t* __restrict__ dst)
{
    int i = blockIdx.x * 256 + threadIdx.x;       // 8-elem chunk id
    int row = i >> 8;                              // 256 chunks per 2048-row
    int c8  = i & 255;
    const float* src;
    if      (row < 2048) src = Wq + (size_t)row * 2048;
    else if (row < 2560) src = Wk + (size_t)(row - 2048) * 2048;
    else if (row < 3072) src = Wv + (size_t)(row - 2560) * 2048;
    else                 src = Wo + (size_t)(row - 3072) * 2048;
    float4 a = *((const float4*)src + c8 * 2);
    float4 b = *((const float4*)src + c8 * 2 + 1);
    ushort_t o[8] = { f2b(a.x), f2b(a.y), f2b(a.z), f2b(a.w),
                      f2b(b.x), f2b(b.y), f2b(b.z), f2b(b.w) };
    *((uint4*)dst + i) = *(const uint4*)o;
}

__global__ __launch_bounds__(256) void concat_bias3(
    const float* __restrict__ bq, const float* __restrict__ bk,
    const float* __restrict__ bv, float* __restrict__ dst)
{
    int i = blockIdx.x * 256 + threadIdx.x;
    if (i < 2048) dst[i] = bq[i];
    else if (i < 2560) dst[i] = bk[i - 2048];
    else if (i < 3072) dst[i] = bv[i - 2560];
}

// ---------------------------------------------------------------
// GEMM: C[M][N] = A[M][K] * W[N][K]^T + bias[N]; bf16 in, f32 acc.
// 128x128 tile, BK=64, 4 waves (2x2 of 64x64), mfma_f32_16x16x32_bf16.
// global_load_lds width=16, linear LDS dest, pre-swizzled global src.
// Chunk (row r, source slot s in 0..7 of 16B) stored at slot s^(r&7).
// 2-barrier loop, K/64 iterations. Bijective XCD swizzle (grid%8==0).
// ---------------------------------------------------------------
template <typename OT>
__global__ __launch_bounds__(256) void gemm_bt(
    const ushort_t* __restrict__ A, const ushort_t* __restrict__ W,
    const float* __restrict__ bias, OT* __restrict__ C,
    int M, int N, int K)
{
    __shared__ __attribute__((aligned(16))) ushort_t sA[8192];
    __shared__ __attribute__((aligned(16))) ushort_t sB[8192];

    const int tid  = threadIdx.x;
    const int lane = tid & 63;
    const int wave = tid >> 6;
    const int nbn  = N >> 7;

    // XCD-aware swizzle: contiguous bm-panels per XCD (grid %8 == 0).
    int nwg = gridDim.x;
    int bid = blockIdx.x;
    int nb  = (nwg & 7) ? bid : ((bid & 7) * (nwg >> 3) + (bid >> 3));
    const int bm = nb / nbn;
    const int bn = nb % nbn;
    const int m0 = bm << 7, n0 = bn << 7;
    const int wm = wave >> 1, wn = wave & 1;

    f32x4 acc[4][4] = {};

    const int frow = lane & 15;
    const int kg   = lane >> 4;           // k-subslot within 32-k half

    // staging: per matrix 1024 chunks of 16B; wave w owns sets t=4w..4w+3,
    // set t covers chunks t*64+lane. r=c>>3, store slot=c&7, src slot=s^(r&7).
    const ushort_t* gA[4]; const ushort_t* gB[4];
    ushort_t* lA[4]; ushort_t* lB[4];
#pragma unroll
    for (int j = 0; j < 4; ++j) {
        int t = wave * 4 + j;
        int c = t * 64 + lane;
        int r = c >> 3, s = c & 7;
        int ksrc = s ^ (r & 7);
        gA[j] = A + (size_t)(m0 + r) * K + ksrc * 8;
        gB[j] = W + (size_t)(n0 + r) * K + ksrc * 8;
        lA[j] = sA + t * 512;
        lB[j] = sB + t * 512;
    }

    for (int k0 = 0; k0 < K; k0 += 64) {
        if (k0) __syncthreads();             // prev-iter LDS reads drained
#pragma unroll
        for (int j = 0; j < 4; ++j) gload_lds16(gA[j] + k0, lA[j]);
#pragma unroll
        for (int j = 0; j < 4; ++j) gload_lds16(gB[j] + k0, lB[j]);
        __syncthreads();                     // loads landed

        bf16x8 af[4][2], bfr[4][2];
#pragma unroll
        for (int mi = 0; mi < 4; ++mi)
#pragma unroll
            for (int kk = 0; kk < 2; ++kk) {
                int r = (wm << 6) + (mi << 4) + frow;
                int sl = (kk * 4 + kg) ^ (r & 7);
                af[mi][kk] = *(const bf16x8*)(sA + (r * 8 + sl) * 8);
            }
#pragma unroll
        for (int ni = 0; ni < 4; ++ni)
#pragma unroll
            for (int kk = 0; kk < 2; ++kk) {
                int r = (wn << 6) + (ni << 4) + frow;
                int sl = (kk * 4 + kg) ^ (r & 7);
                bfr[ni][kk] = *(const bf16x8*)(sB + (r * 8 + sl) * 8);
            }
#pragma unroll
        for (int kk = 0; kk < 2; ++kk)
#pragma unroll
            for (int mi = 0; mi < 4; ++mi)
#pragma unroll
                for (int ni = 0; ni < 4; ++ni)
                    acc[mi][ni] = __builtin_amdgcn_mfma_f32_16x16x32_bf16(
                        af[mi][kk], bfr[ni][kk], acc[mi][ni], 0, 0, 0);
    }

    // D: col = lane&15, row = (lane>>4)*4 + reg  [m89-verified]
    const int orow = (lane >> 4) << 2;
    const int ocol = lane & 15;
#pragma unroll
    for (int ni = 0; ni < 4; ++ni) {
        int col = n0 + (wn << 6) + (ni << 4) + ocol;
        float bvf = bias[col];
#pragma unroll
        for (int mi = 0; mi < 4; ++mi) {
#pragma unroll
            for (int r = 0; r < 4; ++r) {
                int row = m0 + (wm << 6) + (mi << 4) + orow + r;
                float val = acc[mi][ni][r] + bvf;
                if constexpr (sizeof(OT) == 2) C[(size_t)row * N + col] = f2b(val);
                else                           C[(size_t)row * N + col] = val;
            }
        }
    }
}

// ---------------------------------------------------------------
// Fused RMSNorm + RoPE, IN-PLACE on qkv [M][3072].
// Slots 0..15 = q heads (qw), 16..19 = k heads (kw); v untouched.
// ---------------------------------------------------------------
__global__ __launch_bounds__(128) void rmsrope(
    ushort_t* __restrict__ qkv, const float* __restrict__ qw,
    const float* __restrict__ kw)
{
    __shared__ float red[2];
    const int d   = threadIdx.x;           // 0..127
    const int blk = blockIdx.x;
    const int bs  = blk / 20;
    const int hh  = blk % 20;
    const int s   = bs & 2047;

    ushort_t* p = qkv + (size_t)bs * NQKV + hh * DK;
    const float* w = (hh < NHEADS) ? qw : kw;

    float x  = b2f(p[d]);
    float ss = x * x;
#pragma unroll
    for (int off = 32; off; off >>= 1) ss += __shfl_xor(ss, off, 64);
    if ((d & 63) == 0) red[d >> 6] = ss;
    __syncthreads();
    float tot = red[0] + red[1];
    float inv = rsqrtf(tot * (1.0f / 128.0f) + 1e-8f);
    float xn  = x * inv * w[d];

    float partner = __shfl_xor(xn, 1, 64);
    float invfreq = exp2f(-(float)(d & ~1) * (13.287712379549449f / 128.0f));
    float angle   = (float)s * invfreq;
    float c = cosf(angle), sn = sinf(angle);
    float o = (d & 1) ? (partner * sn + xn * c) : (xn * c - partner * sn);
    p[d] = f2b(o);
}

// ---------------------------------------------------------------
// MFMA windowed-causal GQA attention on fused qkv [M][3072].
// Block = 256 thr (4 waves), 64 queries of one (b,h); window union
// [i0-64, i0+63] = 128 keys. K/V at col 2048 / 2560.
// ---------------------------------------------------------------
__global__ __launch_bounds__(256) void attn_mfma(
    const ushort_t* __restrict__ qkv, const float* __restrict__ scp,
    ushort_t* __restrict__ ao)
{
    __shared__ __attribute__((aligned(16))) ushort_t sK[16384];   // K tile, then P(f32)
    __shared__ __attribute__((aligned(16))) ushort_t sVT[16384];  // V^T tile

    const int tid  = threadIdx.x;
    const int lane = tid & 63;
    const int w    = tid >> 6;
    const int c    = lane & 15;
    const int g    = lane >> 4;

    const int blk = blockIdx.x;
    const int qt  = blk & 31;
    const int h   = (blk >> 5) & 15;
    const int b   = blk >> 9;
    const int kvh = h >> 2;
    const int i0  = qt << 6;
    const int jb  = i0 - 64;
    const float scale = scp[0];

    // ---- Q fragments straight from global ----
    bf16x8 aq[4];
    {
        const ushort_t* qp = qkv + ((size_t)(b * 2048 + i0 + w * 16 + c)) * NQKV
                                 + h * 128 + g * 8;
#pragma unroll
        for (int ks = 0; ks < 4; ++ks)
            aq[ks] = *(const bf16x8*)(qp + ks * 32);
    }

    // ---- stage K rows [key][d] ----
    const ushort_t* kvb = qkv + ((size_t)b * 2048) * NQKV + 2048 + kvh * 128;
#pragma unroll
    for (int it = 0; it < 8; ++it) {
        int idx = it * 256 + tid;
        int rr = idx >> 4, cc = idx & 15;
        int j = jb + rr; if (j < 0) j = 0;
        uint4 val = *(const uint4*)(kvb + (size_t)j * NQKV + cc * 8);
        int f2v = (rr & 15) ^ ((rr >> 3) & 15);
        *(uint4*)(sK + (rr * 16 + (cc ^ f2v)) * 8) = val;
    }
    // ---- stage V transposed: VT[d][key] ----
#pragma unroll
    for (int it = 0; it < 4; ++it) {
        int task = it * 256 + tid;
        int pp = task >> 4, d8 = task & 15;
        int j0 = jb + 2 * pp;     if (j0 < 0) j0 = 0;
        int j1 = jb + 2 * pp + 1; if (j1 < 0) j1 = 0;
        ushort_t e0[8]; *(uint4*)e0 = *(const uint4*)(kvb + (size_t)j0 * NQKV + 512 + d8 * 8);
        ushort_t e1[8]; *(uint4*)e1 = *(const uint4*)(kvb + (size_t)j1 * NQKV + 512 + d8 * 8);
        int cc = pp >> 2;
#pragma unroll
        for (int jj = 0; jj < 8; ++jj) {
            int rr = d8 * 8 + jj;
            int f2v = (rr & 15) ^ ((rr >> 3) & 15);
            unsigned int word = (unsigned int)e0[jj] | ((unsigned int)e1[jj] << 16);
            *(unsigned int*)(sVT + (rr * 16 + (cc ^ f2v)) * 8 + (pp & 3) * 2) = word;
        }
    }
    __syncthreads();

    // ---- S = Q K^T ----
    f32x4 s[8] = {};
#pragma unroll
    for (int nt = 0; nt < 8; ++nt) {
        int rr = nt * 16 + c;
        int f2v = (rr & 15) ^ ((rr >> 3) & 15);
#pragma unroll
        for (int ks = 0; ks < 4; ++ks) {
            bf16x8 bk = *(const bf16x8*)(sK + (rr * 16 + ((ks * 4 + g) ^ f2v)) * 8);
            s[nt] = __builtin_amdgcn_mfma_f32_16x16x32_bf16(aq[ks], bk, s[nt], 0, 0, 0);
        }
    }

    // ---- mask + row softmax ----
    float linv[4];
#pragma unroll
    for (int r = 0; r < 4; ++r) {
        int qb = w * 16 + g * 4 + r;
#pragma unroll
        for (int nt = 0; nt < 8; ++nt) {
            int jl = nt * 16 + c;
            bool valid = (jl >= qb) && (jl <= qb + 64) && (i0 + jl >= 64);
            s[nt][r] = valid ? s[nt][r] * scale : -1e30f;
        }
        float m = s[0][r];
#pragma unroll
        for (int nt = 1; nt < 8; ++nt) m = fmaxf(m, s[nt][r]);
#pragma unroll
        for (int off = 1; off <= 8; off <<= 1) m = fmaxf(m, __shfl_xor(m, off, 64));
        float sum = 0.f;
#pragma unroll
        for (int nt = 0; nt < 8; ++nt) {
            float e = __expf(s[nt][r] - m);
            s[nt][r] = e;
            sum += e;
        }
#pragma unroll
        for (int off = 1; off <= 8; off <<= 1) sum += __shfl_xor(sum, off, 64);
        linv[r] = 1.0f / sum;
    }

    // ---- P via LDS ----
    __syncthreads();
    float* Pw = (float*)sK + w * 2048;
#pragma unroll
    for (int nt = 0; nt < 8; ++nt) {
#pragma unroll
        for (int r = 0; r < 4; ++r) {
            int q = g * 4 + r;
            int chunk = nt * 4 + (c >> 2);
            Pw[q * 128 + ((chunk ^ (q & 7)) * 4) + (c & 3)] = s[nt][r];
        }
    }

    // ---- O = P V ----
    f32x4 o[8] = {};
#pragma unroll
    for (int kt = 0; kt < 4; ++kt) {
        float pf[8];
#pragma unroll
        for (int e = 0; e < 2; ++e) {
            int chunk = kt * 8 + g * 2 + e;
            f32x4 v4 = *(const f32x4*)(Pw + c * 128 + ((chunk ^ (c & 7)) * 4));
            pf[e * 4 + 0] = v4[0]; pf[e * 4 + 1] = v4[1];
            pf[e * 4 + 2] = v4[2]; pf[e * 4 + 3] = v4[3];
        }
        ushort_t pb[8];
#pragma unroll
        for (int j = 0; j < 8; ++j) pb[j] = f2b(pf[j]);
        bf16x8 pa = *(const bf16x8*)pb;
#pragma unroll
        for (int dt = 0; dt < 8; ++dt) {
            int rr = dt * 16 + c;
            int f2v = (rr & 15) ^ ((rr >> 3) & 15);
            bf16x8 bv = *(const bf16x8*)(sVT + (rr * 16 + ((kt * 4 + g) ^ f2v)) * 8);
            o[dt] = __builtin_amdgcn_mfma_f32_16x16x32_bf16(pa, bv, o[dt], 0, 0, 0);
        }
    }

    // ---- epilogue ----
    const size_t orow0 = (size_t)(b * 2048 + i0 + w * 16);
#pragma unroll
    for (int dt = 0; dt < 8; ++dt) {
#pragma unroll
        for (int r = 0; r < 4; ++r) {
            int q = g * 4 + r;
            ao[(orow0 + q) * 2048 + h * 128 + dt * 16 + c] = f2b(o[dt][r] * linv[r]);
        }
    }
}

// ---------------------------------------------------------------
extern "C" void kernel_launch(void* const* d_in, const int* in_sizes, int n_in,
                              void* d_out, int out_size, void* d_ws, size_t ws_size,
                              hipStream_t stream)
{
    const float* x   = (const float*)d_in[0];
    const float* Wq  = (const float*)d_in[1];
    const float* bq  = (const float*)d_in[2];
    const float* Wk  = (const float*)d_in[3];
    const float* bk  = (const float*)d_in[4];
    const float* Wv  = (const float*)d_in[5];
    const float* bv  = (const float*)d_in[6];
    const float* Wo  = (const float*)d_in[7];
    const float* bo  = (const float*)d_in[8];
    const float* qnw = (const float*)d_in[9];
    const float* knw = (const float*)d_in[10];
    const float* scp = (const float*)d_in[11];
    float* out = (float*)d_out;

    const int M = BATCH * SEQ;             // 4096
    ushort_t* xb    = (ushort_t*)d_ws;                      // M x 2048 (later: ao)
    ushort_t* qkv0  = xb   + (size_t)M * DMODEL;            // M x 3072
    ushort_t* Wqkvb = qkv0 + (size_t)M * NQKV;              // 3072 x 2048
    ushort_t* Wob   = Wqkvb + (size_t)NQKV * DMODEL;        // 2048 x 2048 (contiguous after)
    float*    bqkv  = (float*)(Wob + (size_t)DMODEL * DMODEL); // 3072 f32
    ushort_t* ao    = xb;
    (void)ws_size; (void)in_sizes; (void)n_in; (void)out_size;

    cvt_bf16<<<dim3(4096), 256, 0, stream>>>(x, xb, M * DMODEL / 8);
    cvt_weights<<<dim3(5120), 256, 0, stream>>>(Wq, Wk, Wv, Wo, Wqkvb);
    concat_bias3<<<dim3(12), 256, 0, stream>>>(bq, bk, bv, bqkv);

    gemm_bt<ushort_t><<<dim3((M / 128) * (NQKV / 128)), 256, 0, stream>>>(
        xb, Wqkvb, bqkv, qkv0, M, NQKV, DMODEL);
    rmsrope<<<dim3(M * (NHEADS + NKV)), 128, 0, stream>>>(qkv0, qnw, knw);
    attn_mfma<<<dim3(BATCH * NHEADS * (SEQ / 64)), 256, 0, stream>>>(qkv0, scp, ao);
    gemm_bt<float><<<dim3((M / 128) * (DMODEL / 128)), 256, 0, stream>>>(
        ao, Wob, bo, out, M, DMODEL, DMODEL);
}